// Round 1
// baseline (660.737 us; speedup 1.0000x reference)
//
#include <hip/hip_runtime.h>

#define FD 128   // hidden feature dim
#define OD 64    // output dim

// ---------------- graph preprocessing ----------------

__global__ void zero_kernel(int* __restrict__ a, int n) {
    int i = blockIdx.x * 256 + threadIdx.x;
    if (i < n) a[i] = 0;
}

__global__ void degree_kernel(const int* __restrict__ src, const int* __restrict__ dst,
                              int* __restrict__ dout, int* __restrict__ din, int E) {
    int e = blockIdx.x * 256 + threadIdx.x;
    if (e < E) {
        atomicAdd(&dout[src[e]], 1);
        atomicAdd(&din[dst[e]], 1);
    }
}

__global__ void rsqrt_kernel(const int* __restrict__ dout, const int* __restrict__ din,
                             float* __restrict__ r_out, float* __restrict__ r_in, int N) {
    int i = blockIdx.x * 256 + threadIdx.x;
    if (i < N) {
        r_out[i] = rsqrtf((float)max(dout[i], 1));
        r_in[i]  = rsqrtf((float)max(din[i], 1));
    }
}

// exclusive scan of deg[0..n) into rs[0..n], rs[n] = total. Single block, 1024 threads.
__global__ void scan_kernel(const int* __restrict__ deg, int* __restrict__ rs, int n) {
    __shared__ int wsum[16];
    __shared__ int carry_s;
    int tid = threadIdx.x;
    int lane = tid & 63, w = tid >> 6;
    if (tid == 0) carry_s = 0;
    __syncthreads();
    for (int base = 0; base < n; base += 1024) {
        int i = base + tid;
        int v = (i < n) ? deg[i] : 0;
        int x = v;
        #pragma unroll
        for (int d = 1; d < 64; d <<= 1) {
            int t = __shfl_up(x, d, 64);
            if (lane >= d) x += t;
        }
        if (lane == 63) wsum[w] = x;
        __syncthreads();
        if (w == 0) {
            int s = (lane < 16) ? wsum[lane] : 0;
            #pragma unroll
            for (int d = 1; d < 16; d <<= 1) {
                int t = __shfl_up(s, d, 64);
                if (lane >= d) s += t;
            }
            if (lane < 16) wsum[lane] = s;
        }
        __syncthreads();
        int waveoff = (w == 0) ? 0 : wsum[w - 1];
        int incl = x + waveoff + carry_s;
        if (i < n) rs[i] = incl - v;       // exclusive
        __syncthreads();                   // everyone has read carry_s
        if (tid == 1023) carry_s = incl;   // chunk total (includes old carry)
        __syncthreads();
    }
    if (threadIdx.x == 0) rs[n] = carry_s;
}

__global__ void cursor_kernel(const int* __restrict__ rs, int* __restrict__ cur, int N) {
    int i = blockIdx.x * 256 + threadIdx.x;
    if (i < N) cur[i] = rs[i];
}

__global__ void scatter_kernel(const int* __restrict__ src, const int* __restrict__ dst,
                               int* __restrict__ cur, int* __restrict__ csrc, int E) {
    int e = blockIdx.x * 256 + threadIdx.x;
    if (e < E) {
        int pos = atomicAdd(&cur[dst[e]], 1);
        csrc[pos] = src[e];
    }
}

// ---------------- aggregation (gather over CSR-by-dst) ----------------
// Z[v] = r_dst[v] * sum_{e in in(v)} (SCALE ? r_src[s_e] : 1) * X[s_e]
template <bool SCALE>
__global__ __launch_bounds__(64) void agg_kernel(const float* __restrict__ X,
                                                 const float* __restrict__ r_src,
                                                 const float* __restrict__ r_dst,
                                                 const int* __restrict__ rs,
                                                 const int* __restrict__ csrc,
                                                 float* __restrict__ Z) {
    int v = blockIdx.x;
    int lane = threadIdx.x;          // 64 lanes, 2 floats each = 128 features
    int s0 = rs[v], s1 = rs[v + 1];
    float ax = 0.f, ay = 0.f;
    int e = s0;
    for (; e + 1 < s1; e += 2) {
        int sA = csrc[e], sB = csrc[e + 1];
        const float2* rA = (const float2*)(X + (size_t)sA * FD);
        const float2* rB = (const float2*)(X + (size_t)sB * FD);
        float2 tA = rA[lane];
        float2 tB = rB[lane];
        float wA = SCALE ? r_src[sA] : 1.f;
        float wB = SCALE ? r_src[sB] : 1.f;
        ax += tA.x * wA; ay += tA.y * wA;
        ax += tB.x * wB; ay += tB.y * wB;
    }
    if (e < s1) {
        int sA = csrc[e];
        const float2* rA = (const float2*)(X + (size_t)sA * FD);
        float2 tA = rA[lane];
        float wA = SCALE ? r_src[sA] : 1.f;
        ax += tA.x * wA; ay += tA.y * wA;
    }
    float ri = r_dst[v];
    float2 o; o.x = ax * ri; o.y = ay * ri;
    *((float2*)(Z + (size_t)v * FD) + lane) = o;
}

// ---------------- GEMM: C(MxBN) = A(Mx128) * B(128xBN) + epilogue ----------------
// EPI 0: C = relu(acc + bias[col]) * rowscale[row]
// EPI 1: C = acc + bias[col]
template <int BN, int TN, int EPI>
__global__ __launch_bounds__(256) void gemm_kernel(const float* __restrict__ A,
                                                   const float* __restrict__ B,
                                                   const float* __restrict__ bias,
                                                   const float* __restrict__ rowscale,
                                                   float* __restrict__ C, int M) {
    __shared__ float As[8][128];
    __shared__ float Bs[8][BN];
    const int tid = threadIdx.x;
    const int blk0 = blockIdx.x * 128;
    const int tr = tid >> 4;        // 0..15 row group (8 rows each)
    const int tc = tid & 15;        // 0..15 col group (TN cols each)

    float acc[8][TN];
    #pragma unroll
    for (int i = 0; i < 8; i++)
        #pragma unroll
        for (int j = 0; j < TN; j++) acc[i][j] = 0.f;

    const int lm = tid >> 1;             // 0..127 row for A staging
    const int lka = (tid & 1) * 4;       // k sub-offset
    const int arow = blk0 + lm;
    constexpr int bthr = (8 * BN) / 256; // floats per thread for B staging (4 or 2)
    const int lkb = tid / (BN / bthr);
    const int lnb = (tid % (BN / bthr)) * bthr;

    for (int k0 = 0; k0 < 128; k0 += 8) {
        float4 av = make_float4(0.f, 0.f, 0.f, 0.f);
        if (arow < M) av = *(const float4*)(A + (size_t)arow * 128 + k0 + lka);
        float bv[bthr];
        #pragma unroll
        for (int j = 0; j < bthr; j++) bv[j] = B[(k0 + lkb) * BN + lnb + j];
        __syncthreads();   // previous iter's compute done before overwrite
        As[lka + 0][lm] = av.x;
        As[lka + 1][lm] = av.y;
        As[lka + 2][lm] = av.z;
        As[lka + 3][lm] = av.w;
        #pragma unroll
        for (int j = 0; j < bthr; j++) Bs[lkb][lnb + j] = bv[j];
        __syncthreads();
        #pragma unroll
        for (int kk = 0; kk < 8; kk++) {
            float a[8], b[TN];
            #pragma unroll
            for (int i = 0; i < 8; i++) a[i] = As[kk][tr * 8 + i];
            #pragma unroll
            for (int j = 0; j < TN; j++) b[j] = Bs[kk][tc * TN + j];
            #pragma unroll
            for (int i = 0; i < 8; i++)
                #pragma unroll
                for (int j = 0; j < TN; j++) acc[i][j] += a[i] * b[j];
        }
    }

    #pragma unroll
    for (int i = 0; i < 8; i++) {
        int row = blk0 + tr * 8 + i;
        if (row < M) {
            float rsc = (EPI == 0) ? rowscale[row] : 1.f;
            #pragma unroll
            for (int j = 0; j < TN; j++) {
                float vv = acc[i][j] + bias[tc * TN + j];
                if (EPI == 0) vv = fmaxf(vv, 0.f) * rsc;
                C[(size_t)row * BN + tc * TN + j] = vv;
            }
        }
    }
}

// ---------------- fold W2@Wf, b2@Wf+bf ----------------
__global__ void fold_kernel(const float* __restrict__ W2, const float* __restrict__ Wf,
                            const float* __restrict__ b2, const float* __restrict__ bf,
                            float* __restrict__ Wc, float* __restrict__ bc) {
    int idx = blockIdx.x * 256 + threadIdx.x;
    if (idx < FD * OD) {
        int i = idx / OD, j = idx % OD;
        float s = 0.f;
        for (int k = 0; k < FD; k++) s += W2[i * FD + k] * Wf[k * OD + j];
        Wc[idx] = s;
    }
    if (idx < OD) {
        float s = bf[idx];
        for (int k = 0; k < FD; k++) s += b2[k] * Wf[k * OD + idx];
        bc[idx] = s;
    }
}

// ---------------- launch ----------------
extern "C" void kernel_launch(void* const* d_in, const int* in_sizes, int n_in,
                              void* d_out, int out_size, void* d_ws, size_t ws_size,
                              hipStream_t stream) {
    const float* in_feat = (const float*)d_in[0];
    const int*   src     = (const int*)d_in[1];
    const int*   dst     = (const int*)d_in[2];
    const float* W1      = (const float*)d_in[3];
    const float* b1      = (const float*)d_in[4];
    const float* W2      = (const float*)d_in[5];
    const float* b2      = (const float*)d_in[6];
    const float* Wf      = (const float*)d_in[7];
    const float* bf      = (const float*)d_in[8];
    float* out = (float*)d_out;

    const int N = in_sizes[0] / FD;   // 50000
    const int E = in_sizes[1];        // 1600000

    char* ws = (char*)d_ws;
    size_t off = 0;
    auto alloc = [&](size_t bytes) -> void* {
        void* p = ws + off;
        off += (bytes + 255) / 256 * 256;
        return p;
    };
    int*   deg_out_i = (int*)alloc((size_t)N * 4);
    int*   deg_in_i  = (int*)alloc((size_t)N * 4);
    float* r_out     = (float*)alloc((size_t)N * 4);
    float* r_in      = (float*)alloc((size_t)N * 4);
    int*   row_start = (int*)alloc((size_t)(N + 1) * 4);
    int*   cursor    = (int*)alloc((size_t)N * 4);
    int*   csr_src   = (int*)alloc((size_t)E * 4);
    float* bufA      = (float*)alloc((size_t)N * FD * 4);  // z1 / z2
    float* bufB      = (float*)alloc((size_t)N * FD * 4);  // y1
    float* Wc        = (float*)alloc((size_t)FD * OD * 4);
    float* bc        = (float*)alloc((size_t)OD * 4);
    (void)ws_size; (void)n_in; (void)out_size;

    const int gN = (N + 255) / 256;
    const int gE = (E + 255) / 256;

    // graph preprocessing
    zero_kernel<<<gN, 256, 0, stream>>>(deg_out_i, N);
    zero_kernel<<<gN, 256, 0, stream>>>(deg_in_i, N);
    degree_kernel<<<gE, 256, 0, stream>>>(src, dst, deg_out_i, deg_in_i, E);
    rsqrt_kernel<<<gN, 256, 0, stream>>>(deg_out_i, deg_in_i, r_out, r_in, N);
    scan_kernel<<<1, 1024, 0, stream>>>(deg_in_i, row_start, N);
    cursor_kernel<<<gN, 256, 0, stream>>>(row_start, cursor, N);
    scatter_kernel<<<gE, 256, 0, stream>>>(src, dst, cursor, csr_src, E);

    // fold the two final linear layers (independent; tiny)
    fold_kernel<<<(FD * OD + 255) / 256, 256, 0, stream>>>(W2, Wf, b2, bf, Wc, bc);

    // layer 1: z1 = r_in * Agg(r_out * x) ; y1 = relu(z1 @ W1 + b1) * r_out
    agg_kernel<true><<<N, 64, 0, stream>>>(in_feat, r_out, r_in, row_start, csr_src, bufA);
    gemm_kernel<128, 8, 0><<<(N + 127) / 128, 256, 0, stream>>>(bufA, W1, b1, r_out, bufB, N);

    // layer 2 + final: z2 = r_in * Agg(y1) ; out = z2 @ Wc + bc
    agg_kernel<false><<<N, 64, 0, stream>>>(bufB, r_out, r_in, row_start, csr_src, bufA);
    gemm_kernel<64, 4, 1><<<(N + 127) / 128, 256, 0, stream>>>(bufA, Wc, bc, (const float*)nullptr, out, N);
}

// Round 2
// 608.782 us; speedup vs baseline: 1.0853x; 1.0853x over previous
//
#include <hip/hip_runtime.h>

#define FD 128   // hidden feature dim
#define OD 64    // output dim
#define KC 32    // privatized histogram copies

// ---------------- graph preprocessing ----------------

__global__ void zero_kernel(int* __restrict__ a, int n) {
    int i = blockIdx.x * 256 + threadIdx.x;
    if (i < n) a[i] = 0;
}

// per-copy degree counting: copy k = blockIdx % KC
__global__ void count_kernel(const int* __restrict__ src, const int* __restrict__ dst,
                             int* __restrict__ cnt_out, int* __restrict__ cnt_in,
                             int E, int N) {
    int e = blockIdx.x * 256 + threadIdx.x;
    int k = blockIdx.x & (KC - 1);
    if (e < E) {
        atomicAdd(&cnt_out[k * N + src[e]], 1);
        atomicAdd(&cnt_in [k * N + dst[e]], 1);
    }
}

// sum the KC copies -> deg_in (for scan) + rsqrt factors
__global__ void reduce_deg_kernel(const int* __restrict__ cnt_out, const int* __restrict__ cnt_in,
                                  int* __restrict__ deg_in,
                                  float* __restrict__ r_out, float* __restrict__ r_in, int N) {
    int v = blockIdx.x * 256 + threadIdx.x;
    if (v >= N) return;
    int so = 0, si = 0;
    #pragma unroll
    for (int k = 0; k < KC; k++) {
        so += cnt_out[k * N + v];
        si += cnt_in [k * N + v];
    }
    deg_in[v] = si;
    r_out[v] = rsqrtf((float)max(so, 1));
    r_in[v]  = rsqrtf((float)max(si, 1));
}

// multi-block exclusive scan, phase 1: per-block (1024 elems) scan + block sums
__global__ __launch_bounds__(1024) void scan1_kernel(const int* __restrict__ deg,
                                                     int* __restrict__ rs,
                                                     int* __restrict__ bsum, int n) {
    __shared__ int wsum[16];
    int tid = threadIdx.x;
    int lane = tid & 63, w = tid >> 6;
    int i = blockIdx.x * 1024 + tid;
    int v = (i < n) ? deg[i] : 0;
    int x = v;
    #pragma unroll
    for (int d = 1; d < 64; d <<= 1) {
        int t = __shfl_up(x, d, 64);
        if (lane >= d) x += t;
    }
    if (lane == 63) wsum[w] = x;
    __syncthreads();
    if (w == 0) {
        int s = (lane < 16) ? wsum[lane] : 0;
        #pragma unroll
        for (int d = 1; d < 16; d <<= 1) {
            int t = __shfl_up(s, d, 64);
            if (lane >= d) s += t;
        }
        if (lane < 16) wsum[lane] = s;
    }
    __syncthreads();
    int off = (w == 0) ? 0 : wsum[w - 1];
    int incl = x + off;
    if (i < n) rs[i] = incl - v;           // block-local exclusive
    if (tid == 1023) bsum[blockIdx.x] = incl;
}

// phase 2: exclusive scan of block sums (nb <= 64 fast path; serial fallback)
__global__ __launch_bounds__(64) void scan2_kernel(int* __restrict__ bsum, int nb) {
    int lane = threadIdx.x;
    if (nb <= 64) {
        int v = (lane < nb) ? bsum[lane] : 0;
        int x = v;
        #pragma unroll
        for (int d = 1; d < 64; d <<= 1) {
            int t = __shfl_up(x, d, 64);
            if (lane >= d) x += t;
        }
        if (lane < nb) bsum[lane] = x - v;
    } else if (lane == 0) {
        int run = 0;
        for (int b = 0; b < nb; b++) { int t = bsum[b]; bsum[b] = run; run += t; }
    }
}

// phase 3: add block offsets; also write rs[n] = E (sum of in-degrees == edge count)
__global__ void scan3_kernel(int* __restrict__ rs, const int* __restrict__ bsum, int n, int E) {
    int i = blockIdx.x * 256 + threadIdx.x;
    if (i < n) rs[i] += bsum[i >> 10];
    if (i == 0) rs[n] = E;
}

// per-copy cursors: cur[k][v] = rs[v] + sum_{k'<k} cnt_in[k'][v]
__global__ void cursors_kernel(const int* __restrict__ rs, const int* __restrict__ cnt_in,
                               int* __restrict__ cur, int N) {
    int v = blockIdx.x * 256 + threadIdx.x;
    if (v >= N) return;
    int run = rs[v];
    #pragma unroll
    for (int k = 0; k < KC; k++) {
        cur[k * N + v] = run;
        run += cnt_in[k * N + v];
    }
}

__global__ void scatter_kernel(const int* __restrict__ src, const int* __restrict__ dst,
                               int* __restrict__ cur, int* __restrict__ csrc, int E, int N) {
    int e = blockIdx.x * 256 + threadIdx.x;
    int k = blockIdx.x & (KC - 1);
    if (e < E) {
        int pos = atomicAdd(&cur[k * N + dst[e]], 1);
        csrc[pos] = src[e];
    }
}

// ---------------- aggregation (gather over CSR-by-dst) ----------------
// Z[v] = r_dst[v] * sum_{e in in(v)} (SCALE ? r_src[s_e] : 1) * X[s_e]
template <bool SCALE>
__global__ __launch_bounds__(64) void agg_kernel(const float* __restrict__ X,
                                                 const float* __restrict__ r_src,
                                                 const float* __restrict__ r_dst,
                                                 const int* __restrict__ rs,
                                                 const int* __restrict__ csrc,
                                                 float* __restrict__ Z) {
    int v = blockIdx.x;
    int lane = threadIdx.x;          // 64 lanes, 2 floats each = 128 features
    int s0 = rs[v], s1 = rs[v + 1];
    float ax = 0.f, ay = 0.f;
    int e = s0;
    for (; e + 4 <= s1; e += 4) {
        int i0 = csrc[e], i1 = csrc[e + 1], i2 = csrc[e + 2], i3 = csrc[e + 3];
        float2 t0 = ((const float2*)(X + (size_t)i0 * FD))[lane];
        float2 t1 = ((const float2*)(X + (size_t)i1 * FD))[lane];
        float2 t2 = ((const float2*)(X + (size_t)i2 * FD))[lane];
        float2 t3 = ((const float2*)(X + (size_t)i3 * FD))[lane];
        float w0 = SCALE ? r_src[i0] : 1.f;
        float w1 = SCALE ? r_src[i1] : 1.f;
        float w2 = SCALE ? r_src[i2] : 1.f;
        float w3 = SCALE ? r_src[i3] : 1.f;
        ax += t0.x * w0; ay += t0.y * w0;
        ax += t1.x * w1; ay += t1.y * w1;
        ax += t2.x * w2; ay += t2.y * w2;
        ax += t3.x * w3; ay += t3.y * w3;
    }
    for (; e < s1; e++) {
        int i0 = csrc[e];
        float2 t0 = ((const float2*)(X + (size_t)i0 * FD))[lane];
        float w0 = SCALE ? r_src[i0] : 1.f;
        ax += t0.x * w0; ay += t0.y * w0;
    }
    float ri = r_dst[v];
    float2 o; o.x = ax * ri; o.y = ay * ri;
    *((float2*)(Z + (size_t)v * FD) + lane) = o;
}

// ---------------- GEMM: C(MxBN) = A(Mx128) * B(128xBN) + epilogue ----------------
// EPI 0: C = relu(acc + bias[col]) * rowscale[row]
// EPI 1: C = acc + bias[col]
template <int BN, int TN, int EPI>
__global__ __launch_bounds__(256) void gemm_kernel(const float* __restrict__ A,
                                                   const float* __restrict__ B,
                                                   const float* __restrict__ bias,
                                                   const float* __restrict__ rowscale,
                                                   float* __restrict__ C, int M) {
    __shared__ float As[8][128];
    __shared__ float Bs[8][BN];
    const int tid = threadIdx.x;
    const int blk0 = blockIdx.x * 128;
    const int tr = tid >> 4;        // 0..15 row group (8 rows each)
    const int tc = tid & 15;        // 0..15 col group (TN cols each)

    float acc[8][TN];
    #pragma unroll
    for (int i = 0; i < 8; i++)
        #pragma unroll
        for (int j = 0; j < TN; j++) acc[i][j] = 0.f;

    const int lm = tid >> 1;             // 0..127 row for A staging
    const int lka = (tid & 1) * 4;       // k sub-offset
    const int arow = blk0 + lm;
    constexpr int bthr = (8 * BN) / 256; // floats per thread for B staging (4 or 2)
    const int lkb = tid / (BN / bthr);
    const int lnb = (tid % (BN / bthr)) * bthr;

    for (int k0 = 0; k0 < 128; k0 += 8) {
        float4 av = make_float4(0.f, 0.f, 0.f, 0.f);
        if (arow < M) av = *(const float4*)(A + (size_t)arow * 128 + k0 + lka);
        float bv[bthr];
        #pragma unroll
        for (int j = 0; j < bthr; j++) bv[j] = B[(k0 + lkb) * BN + lnb + j];
        __syncthreads();   // previous iter's compute done before overwrite
        As[lka + 0][lm] = av.x;
        As[lka + 1][lm] = av.y;
        As[lka + 2][lm] = av.z;
        As[lka + 3][lm] = av.w;
        #pragma unroll
        for (int j = 0; j < bthr; j++) Bs[lkb][lnb + j] = bv[j];
        __syncthreads();
        #pragma unroll
        for (int kk = 0; kk < 8; kk++) {
            float a[8], b[TN];
            #pragma unroll
            for (int i = 0; i < 8; i++) a[i] = As[kk][tr * 8 + i];
            #pragma unroll
            for (int j = 0; j < TN; j++) b[j] = Bs[kk][tc * TN + j];
            #pragma unroll
            for (int i = 0; i < 8; i++)
                #pragma unroll
                for (int j = 0; j < TN; j++) acc[i][j] += a[i] * b[j];
        }
    }

    #pragma unroll
    for (int i = 0; i < 8; i++) {
        int row = blk0 + tr * 8 + i;
        if (row < M) {
            float rsc = (EPI == 0) ? rowscale[row] : 1.f;
            #pragma unroll
            for (int j = 0; j < TN; j++) {
                float vv = acc[i][j] + bias[tc * TN + j];
                if (EPI == 0) vv = fmaxf(vv, 0.f) * rsc;
                C[(size_t)row * BN + tc * TN + j] = vv;
            }
        }
    }
}

// ---------------- fold W2@Wf, b2@Wf+bf ----------------
__global__ void fold_kernel(const float* __restrict__ W2, const float* __restrict__ Wf,
                            const float* __restrict__ b2, const float* __restrict__ bf,
                            float* __restrict__ Wc, float* __restrict__ bc) {
    int idx = blockIdx.x * 256 + threadIdx.x;
    if (idx < FD * OD) {
        int i = idx / OD, j = idx % OD;
        float s = 0.f;
        for (int k = 0; k < FD; k++) s += W2[i * FD + k] * Wf[k * OD + j];
        Wc[idx] = s;
    }
    if (idx < OD) {
        float s = bf[idx];
        for (int k = 0; k < FD; k++) s += b2[k] * Wf[k * OD + idx];
        bc[idx] = s;
    }
}

// ---------------- launch ----------------
extern "C" void kernel_launch(void* const* d_in, const int* in_sizes, int n_in,
                              void* d_out, int out_size, void* d_ws, size_t ws_size,
                              hipStream_t stream) {
    const float* in_feat = (const float*)d_in[0];
    const int*   src     = (const int*)d_in[1];
    const int*   dst     = (const int*)d_in[2];
    const float* W1      = (const float*)d_in[3];
    const float* b1      = (const float*)d_in[4];
    const float* W2      = (const float*)d_in[5];
    const float* b2      = (const float*)d_in[6];
    const float* Wf      = (const float*)d_in[7];
    const float* bf      = (const float*)d_in[8];
    float* out = (float*)d_out;

    const int N = in_sizes[0] / FD;   // 50000
    const int E = in_sizes[1];        // 1600000

    char* ws = (char*)d_ws;
    size_t off = 0;
    auto alloc = [&](size_t bytes) -> void* {
        void* p = ws + off;
        off += (bytes + 255) / 256 * 256;
        return p;
    };
    int*   cnt_out   = (int*)alloc((size_t)KC * N * 4);
    int*   cnt_in    = (int*)alloc((size_t)KC * N * 4);
    int*   cur       = (int*)alloc((size_t)KC * N * 4);
    int*   deg_in_i  = (int*)alloc((size_t)N * 4);
    float* r_out     = (float*)alloc((size_t)N * 4);
    float* r_in      = (float*)alloc((size_t)N * 4);
    int*   row_start = (int*)alloc((size_t)(N + 1) * 4);
    int*   bsum      = (int*)alloc((size_t)256 * 4);
    int*   csr_src   = (int*)alloc((size_t)E * 4);
    float* bufA      = (float*)alloc((size_t)N * FD * 4);  // z1 / z2
    float* bufB      = (float*)alloc((size_t)N * FD * 4);  // y1
    float* Wc        = (float*)alloc((size_t)FD * OD * 4);
    float* bc        = (float*)alloc((size_t)OD * 4);
    (void)ws_size; (void)n_in; (void)out_size;

    const int gN = (N + 255) / 256;
    const int gE = (E + 255) / 256;
    const int nb = (N + 1023) / 1024;   // scan blocks

    // graph preprocessing (privatized counting sort by dst)
    zero_kernel<<<(2 * KC * N + 255) / 256, 256, 0, stream>>>(cnt_out, 2 * KC * N);
    count_kernel<<<gE, 256, 0, stream>>>(src, dst, cnt_out, cnt_in, E, N);
    reduce_deg_kernel<<<gN, 256, 0, stream>>>(cnt_out, cnt_in, deg_in_i, r_out, r_in, N);
    scan1_kernel<<<nb, 1024, 0, stream>>>(deg_in_i, row_start, bsum, N);
    scan2_kernel<<<1, 64, 0, stream>>>(bsum, nb);
    scan3_kernel<<<gN, 256, 0, stream>>>(row_start, bsum, N, E);
    cursors_kernel<<<gN, 256, 0, stream>>>(row_start, cnt_in, cur, N);
    scatter_kernel<<<gE, 256, 0, stream>>>(src, dst, cur, csr_src, E, N);

    // fold the two final linear layers (independent; tiny)
    fold_kernel<<<(FD * OD + 255) / 256, 256, 0, stream>>>(W2, Wf, b2, bf, Wc, bc);

    // layer 1: z1 = r_in * Agg(r_out * x) ; y1 = relu(z1 @ W1 + b1) * r_out
    agg_kernel<true><<<N, 64, 0, stream>>>(in_feat, r_out, r_in, row_start, csr_src, bufA);
    gemm_kernel<128, 8, 0><<<(N + 127) / 128, 256, 0, stream>>>(bufA, W1, b1, r_out, bufB, N);

    // layer 2 + final: z2 = r_in * Agg(y1) ; out = z2 @ Wc + bc
    agg_kernel<false><<<N, 64, 0, stream>>>(bufB, r_out, r_in, row_start, csr_src, bufA);
    gemm_kernel<64, 4, 1><<<(N + 127) / 128, 256, 0, stream>>>(bufA, Wc, bc, (const float*)nullptr, out, N);
}